// Round 17
// baseline (144.337 us; speedup 1.0000x reference)
//
#include <hip/hip_runtime.h>
#include <hip/hip_bf16.h>

// N=100000, E=3200000, C=4, H=64. f32 inputs; edge_index int32;
// output concat(pm10_next[N], delta[N]) f32.
//
// R22 = R18/R21 champion (reproduced 141.8/142.3us) + ONE change:
//   ksh 3 -> 2 (KPART 8 -> 4). Arithmetic: at KPART=8 each part-block
//   runs only ~4 pipeline iters but pays a full prologue (512 drows
//   loads = 16KB, wfrag loads, sync) + finalize epilogue -> ~30-40% of
//   block time. KPART=4 halves prologue count + drows traffic (50->25MB
//   L2 reads) + finalize skew (3 waiters not 7). 1564 blocks vs ~1024
//   co-resident slots.
// Ledger: R20 boundary cost ~1us (refuted 10-15). R19 etab penalty.
// R17 period-4 regressed; period-3 optimum. R16 coop 2.5x slower.
// R14 >4 blocks/CU thrashes L2. R13 random atomics ~31B HBM each.
// R11 per-block __threadfence = flush storm.

#define HID    64
#define EPSV   1e-8f
#define BNODES 256
#define CAP    10240        // mean 8192, sigma ~90 -> +22 sigma
#define MAXB   512
#define BLK_SC 512
#define RPT_SC 25           // edges held per scatter thread
#define LSTAGE (BLK_SC * RPT_SC)   // 12800 payloads staged in LDS
#define BLK_C  256
#define SLOTW  20           // dwords per staged edge slot (80B, 16B aligned)
#define OVF_CAP 65536

typedef _Float16 half8 __attribute__((ext_vector_type(8)));
typedef _Float16 half2_t __attribute__((ext_vector_type(2)));
typedef float f32x4 __attribute__((ext_vector_type(4)));

__device__ __forceinline__ unsigned int packh2(float a, float b) {
    union { half2_t h; unsigned int u; } v;
    v.h = half2_t{(_Float16)a, (_Float16)b};
    return v.u;
}

__device__ __forceinline__ void feat_from_rows(float4 xs, float4 ps4,
                                               float4 xd, float4 pd4,
                                               float* f) {
    float d0 = ps4.x - pd4.x;
    float d1 = ps4.y - pd4.y;
    float dist = sqrtf(fmaf(d0, d0, fmaf(d1, d1, EPSV)));
    float inv = 1.0f / dist;
    float wind = (xs.y * d0 + xs.z * d1) * inv;
    f[0] = xd.x; f[1] = xd.y; f[2] = xd.z; f[3] = xd.w;
    f[4] = xs.x; f[5] = xs.y; f[6] = xs.z; f[7] = xs.w;
    f[8] = wind; f[9] = dist;
}

__device__ __forceinline__ float mlp_scalar_g(const float* __restrict__ mlp_w,
                                              const float* __restrict__ mlp_b,
                                              const float* __restrict__ head_w,
                                              const float* f) {
    float sacc = 0.0f;
    for (int h = 0; h < HID; h++) {
        const float* wr = mlp_w + h * 10;
        float a = mlp_b[h];
        a = fmaf(wr[0], f[0], a); a = fmaf(wr[1], f[1], a);
        a = fmaf(wr[2], f[2], a); a = fmaf(wr[3], f[3], a);
        a = fmaf(wr[4], f[4], a); a = fmaf(wr[5], f[5], a);
        a = fmaf(wr[6], f[6], a); a = fmaf(wr[7], f[7], a);
        a = fmaf(wr[8], f[8], a); a = fmaf(wr[9], f[9], a);
        a = fmaxf(a, 0.0f);
        sacc = fmaf(head_w[h], a, sacc);
    }
    return sacc;
}

// ---------------- scatter (+prep fused): one-pass counting sort ----------------
__global__ __launch_bounds__(BLK_SC) void scatter_kernel(
    const int* __restrict__ srcs, const int* __restrict__ dsts,
    int E, int B, int N,
    const float4* __restrict__ x, const float2* __restrict__ pos,
    const float* __restrict__ mlp_w,
    float4* __restrict__ xpos, uint4* __restrict__ wbuf,
    unsigned long long* g_ptr64, unsigned int* __restrict__ sorted,
    int2* __restrict__ ovf, int* ovf_cnt)
{
    __shared__ int hist[MAXB];          // counts (atomic returns = rank)
    __shared__ int base[MAXB];          // global base per bucket (this block)
    __shared__ int pfx[MAXB];           // local exclusive prefix
    __shared__ int wsum[BLK_SC / 64];
    __shared__ unsigned int lpay[LSTAGE];   // payloads, local-sorted order
    __shared__ unsigned int ldst[LSTAGE];   // global dest indices

    int tid  = threadIdx.x;
    int lane = tid & 63;
    int wid  = tid >> 6;
    int lo = blockIdx.x * LSTAGE;

    int es[RPT_SC], ed[RPT_SC];
    bool ev[RPT_SC];
    #pragma unroll
    for (int r = 0; r < RPT_SC; r++) {
        int e = lo + r * BLK_SC + tid;
        bool okr = (e < E);
        ev[r] = okr;
        int ee = okr ? e : 0;
        es[r] = srcs[ee];
        ed[r] = dsts[ee];
    }

    for (int b2 = tid; b2 < MAXB; b2 += BLK_SC) hist[b2] = 0;

    // fused prep: pack x+pos into xpos rows (block-sliced)
    {
        int nper = (N + gridDim.x - 1) / gridDim.x;
        int n0 = blockIdx.x * nper;
        int n1 = min(n0 + nper, N);
        for (int n = n0 + tid; n < n1; n += BLK_SC) {
            float4 xr = x[n];
            float2 pr = pos[n];
            xpos[2 * n]     = xr;
            xpos[2 * n + 1] = make_float4(pr.x, pr.y, 0.0f, 0.0f);
        }
    }
    // fused prep: block 0 builds f16 weight fragments (A-operand layout)
    if (blockIdx.x == 0 && tid < 64) {
        int colw = tid & 15, quadw = tid >> 4;
        #pragma unroll
        for (int c = 0; c < 4; c++) {
            int h = c * 16 + colw;
            half8 wf = half8{0, 0, 0, 0, 0, 0, 0, 0};
            if (quadw == 0) {
                #pragma unroll
                for (int j = 0; j < 8; j++) wf[j] = (_Float16)mlp_w[h * 10 + j];
            } else if (quadw == 1) {
                wf[0] = (_Float16)mlp_w[h * 10 + 8];
                wf[1] = (_Float16)mlp_w[h * 10 + 9];
            }
            union { half8 h8; uint4 u4; } cv;
            cv.h8 = wf;
            wbuf[c * 64 + tid] = cv.u4;
        }
    }
    __syncthreads();

    // Phase 1: single atomic pass; atomic return IS the rank.
    // Reuse regs: es[r] <- payload, ed[r] <- (bucket<<14)|rank.
    #pragma unroll
    for (int r = 0; r < RPT_SC; r++) {
        if (ev[r]) {
            int b = ed[r] >> 8;
            int rk = atomicAdd(&hist[b], 1);
            es[r] = (es[r] << 8) | (ed[r] & 255);
            ed[r] = (b << 14) | rk;       // b<=511 (9b), rk<12800 (14b)
        }
    }
    __syncthreads();

    // Phase 2: global reservation (u64-paired) + local exclusive scan
    int PB = (B + 1) >> 1;
    for (int p = tid; p < PB; p += BLK_SC) {
        int b0 = 2 * p, b1 = 2 * p + 1;
        unsigned long long h0 = (unsigned int)hist[b0];
        unsigned long long h1 = (b1 < B) ? (unsigned int)hist[b1] : 0ull;
        unsigned long long comb = h0 | (h1 << 32);
        unsigned long long old = 0ull;
        if (comb) old = atomicAdd(&g_ptr64[p], comb);
        base[b0] = (int)(old & 0xffffffffull);
        if (b1 < B) base[b1] = (int)(old >> 32);
    }
    int v = hist[tid];          // MAXB == BLK_SC: one bucket per thread
    int xs_ = v;
    #pragma unroll
    for (int m = 1; m < 64; m <<= 1) {
        int y = __shfl_up(xs_, m, 64);
        if (lane >= m) xs_ += y;
    }
    if (lane == 63) wsum[wid] = xs_;
    __syncthreads();
    if (tid == 0) {
        int a = 0;
        #pragma unroll
        for (int j = 0; j < BLK_SC / 64; j++) { int t = wsum[j]; wsum[j] = a; a += t; }
    }
    __syncthreads();
    pfx[tid] = wsum[wid] + xs_ - v;
    __syncthreads();

    // Phase 3: stage payload + precomputed global destination
    #pragma unroll
    for (int r = 0; r < RPT_SC; r++) {
        if (ev[r]) {
            int b  = ed[r] >> 14;
            int rk = ed[r] & 0x3FFF;
            int p  = pfx[b] + rk;
            unsigned int pay = (unsigned int)es[r];
            lpay[p] = pay;
            int rel = base[b] + rk;
            if (rel < CAP) {
                ldst[p] = (unsigned int)b * CAP + (unsigned int)rel;
            } else {
                ldst[p] = 0xFFFFFFFFu;
                int o = atomicAdd(ovf_cnt, 1);
                if (o < OVF_CAP)
                    ovf[o] = make_int2((int)(pay >> 8), (b << 8) | (int)(pay & 255u));
            }
        }
    }
    __syncthreads();

    // Phase 4: dense block-linear copy-out (full lane util, coalesced dest)
    int cnt_blk = min(E - lo, LSTAGE);
    for (int t = tid; t < cnt_blk; t += BLK_SC) {
        unsigned int d = ldst[t];
        if (d != 0xFFFFFFFFu) sorted[d] = lpay[t];
    }
}

// ------- compute: MFMA MLP + bucket reduce + fence-free fused finalize -------
__global__ __launch_bounds__(BLK_C, 4) void compute_kernel(
    const float4* __restrict__ xpos,
    const uint4* __restrict__ wbuf,
    const float* __restrict__ mlp_w, const float* __restrict__ mlp_b,
    const float* __restrict__ head_w, const float* __restrict__ head_b,
    const unsigned int* __restrict__ sorted,
    const unsigned long long* __restrict__ g_ptr64,
    const int2* __restrict__ ovf, const int* __restrict__ ovf_cnt,
    float* __restrict__ delta1, int* __restrict__ bdone,
    float* __restrict__ out, int ksh, int N)
{
    // Per-wave B staging: 64 slots x 20 dwords. Dwords 0-4: f16x2 feats
    // k0..k9; 5-15: zeros (k10..k31).
    __shared__ __align__(16) unsigned int stage[4 * 64 * SLOTW];   // 20 KB
    __shared__ __align__(16) float4 drows[2 * BNODES];             // 8 KB dst rows
    __shared__ float acc[BNODES];
    __shared__ int lastflag;
    int tid  = threadIdx.x;
    int wave = tid >> 6;
    int lane = tid & 63;
    int col  = lane & 15;
    int quad = lane >> 4;
    int wbase = wave * 64 * SLOTW;

    int b    = blockIdx.x >> ksh;
    int part = blockIdx.x & ((1 << ksh) - 1);
    int nbase = b << 8;

    acc[tid] = 0.0f;

    // stage this bucket's 256 dst rows (clamped for the tail bucket)
    {
        int lim = 2 * N - 1;
        drows[tid]       = xpos[min(2 * nbase + tid, lim)];
        drows[tid + 256] = xpos[min(2 * nbase + tid + 256, lim)];
    }

    {   // zero the static-zero region of this lane's slot (once)
        unsigned int* slotp = &stage[wbase + lane * SLOTW];
        slotp[5] = 0u;
        *(uint2*)(slotp + 6) = make_uint2(0u, 0u);
        *(uint4*)(slotp + 8) = make_uint4(0u, 0u, 0u, 0u);
        *(uint4*)(slotp + 12) = make_uint4(0u, 0u, 0u, 0u);
    }

    // A-operand weight fragments: 4 vector loads from precomputed buffer
    half8 wfr[4];
    f32x4 bias4[4], hw4[4];
    #pragma unroll
    for (int c = 0; c < 4; c++) {
        union { uint4 u4; half8 h8; } cv;
        cv.u4 = wbuf[c * 64 + lane];
        wfr[c] = cv.h8;
        bias4[c] = *(const f32x4*)&mlp_b[c * 16 + quad * 4];
        hw4[c]   = *(const f32x4*)&head_w[c * 16 + quad * 4];
    }
    __syncthreads();

    unsigned long long gp = g_ptr64[b >> 1];
    int cnt = (b & 1) ? (int)(gp >> 32) : (int)(gp & 0xffffffffull);
    cnt = min(cnt, CAP);
    int e0 = (cnt * part) >> ksh;
    int e1 = (cnt * (part + 1)) >> ksh;
    const unsigned int* sp = sorted + (size_t)b * CAP;

    if (e0 < e1) {
        // Period-3 software pipeline (R10-proven; R17's period-4 regressed):
        //   step k: consume (p_k, x_k); gather x_{k+1} from p_{k+1};
        //           prefetch p_{k+2}.
        unsigned int p0, p1, p2;
        float4 xA, pA, xB, pB, xC, pC;
        {
            int i = e0 + tid;
            p0 = sp[(i < e1) ? i : e0];
            int i1 = i + BLK_C;
            p1 = sp[(i1 < e1) ? i1 : e0];
            int s0 = (int)(p0 >> 8);
            xA = xpos[2 * s0];
            pA = xpos[2 * s0 + 1];
        }

        auto body = [&](int i0, unsigned int pc, unsigned int pn,
                        unsigned int& pn2, float4 xc, float4 psc,
                        float4& xn, float4& psn) {
            bool cok = (i0 + tid) < e1;
            int dl = (int)(pc & 255u);
            // prefetch payload 2 ahead + gathers for next iter (independent)
            int i2 = i0 + 2 * BLK_C + tid;
            pn2 = sp[(i2 < e1) ? i2 : e0];
            int sn = (int)(pn >> 8);
            xn  = xpos[2 * sn];
            psn = xpos[2 * sn + 1];
            // current features: dst side from LDS
            float4 xd  = drows[2 * dl];
            float4 pd4 = drows[2 * dl + 1];
            float f[10];
            feat_from_rows(xc, psc, xd, pd4, f);
            unsigned int* slotp = &stage[wbase + lane * SLOTW];
            *(uint4*)slotp = make_uint4(packh2(f[0], f[1]), packh2(f[2], f[3]),
                                        packh2(f[4], f[5]), packh2(f[6], f[7]));
            slotp[4] = packh2(f[8], f[9]);

            float mysum = 0.0f;
            #pragma unroll
            for (int eg = 0; eg < 4; eg++) {
                const half8 fb = *(const half8*)&stage[wbase + (eg * 16 + col) * SLOTW + quad * 4];
                float sacc = 0.0f;
                #pragma unroll
                for (int c = 0; c < 4; c++) {
                    f32x4 d = __builtin_amdgcn_mfma_f32_16x16x32_f16(wfr[c], fb, bias4[c], 0, 0, 0);
                    sacc = fmaf(hw4[c][0], fmaxf(d[0], 0.f), sacc);
                    sacc = fmaf(hw4[c][1], fmaxf(d[1], 0.f), sacc);
                    sacc = fmaf(hw4[c][2], fmaxf(d[2], 0.f), sacc);
                    sacc = fmaf(hw4[c][3], fmaxf(d[3], 0.f), sacc);
                }
                sacc += __shfl_xor(sacc, 16, 64);
                sacc += __shfl_xor(sacc, 32, 64);
                if (quad == eg) mysum = sacc;
            }
            if (cok) atomicAdd(&acc[dl], mysum);   // ds_add_f32
        };

        int i0 = e0;
        for (;;) {
            body(i0, p0, p1, p2, xA, pA, xB, pB);   // consume p0/xA
            i0 += BLK_C; if (i0 >= e1) break;
            body(i0, p1, p2, p0, xB, pB, xC, pC);   // consume p1/xB
            i0 += BLK_C; if (i0 >= e1) break;
            body(i0, p2, p0, p1, xC, pC, xA, pA);   // consume p2/xC
            i0 += BLK_C; if (i0 >= e1) break;
        }
    }
    __syncthreads();

    // accumulate this part's bucket sums into the single coherent plane.
    // Atomics execute at the memory-side coherent point -> visible to all
    // XCDs once complete; NO threadfence (= no L2 flush) needed.
    {
        int n = nbase + tid;
        if (n < N && acc[tid] != 0.0f)
            unsafeAtomicAdd(&delta1[n], acc[tid]);
    }

    // fused overflow path (normally *ovf_cnt == 0); atomic adds, same plane
    if (part == 0) {
        int oc = min(*ovf_cnt, OVF_CAP);
        for (int idx = tid; idx < oc; idx += BLK_C) {
            int2 sd = ovf[idx];
            if ((sd.y >> 8) == b && sd.y < N) {
                float f[10];
                feat_from_rows(xpos[2 * sd.x], xpos[2 * sd.x + 1],
                               xpos[2 * sd.y], xpos[2 * sd.y + 1], f);
                unsafeAtomicAdd(&delta1[sd.y], mlp_scalar_g(mlp_w, mlp_b, head_w, f));
            }
        }
    }

    // wait for OWN atomics only (cheap; they are globally visible once
    // vmcnt retires them), then signal; last arriving part finalizes.
    asm volatile("s_waitcnt vmcnt(0)" ::: "memory");
    __syncthreads();
    if (tid == 0) {
        int prev = atomicAdd(&bdone[b], 1);
        lastflag = (prev == (1 << ksh) - 1) ? 1 : 0;
    }
    __syncthreads();
    if (lastflag) {
        int n = nbase + tid;
        if (n < N) {
            // coherent read of the fully-accumulated value
            float delta = atomicAdd(&delta1[n], 0.0f) + head_b[0];
            float v = drows[2 * tid].x + delta;   // x[n].x still in LDS
            float sp = fmaxf(v, 0.0f) + log1pf(expf(-fabsf(v)));
            out[n] = sp;
            out[N + n] = delta;
        }
    }
}

// ---------------- fallback path (ws too small) ----------------
__global__ __launch_bounds__(256) void edge_kernel_fallback(
    const float4* __restrict__ x, const float2* __restrict__ pos,
    const float* __restrict__ mlp_w, const float* __restrict__ mlp_b,
    const float* __restrict__ head_w,
    const int* __restrict__ srcs, const int* __restrict__ dsts,
    float* __restrict__ delta_acc, int E)
{
    long e = (long)blockIdx.x * 256 + threadIdx.x;
    if (e >= E) return;
    int s = srcs[e], d = dsts[e];
    float4 xs = x[s], xd = x[d];
    float2 ps = pos[s], pd = pos[d];
    float f[10];
    feat_from_rows(xs, make_float4(ps.x, ps.y, 0, 0),
                   xd, make_float4(pd.x, pd.y, 0, 0), f);
    unsafeAtomicAdd(&delta_acc[d], mlp_scalar_g(mlp_w, mlp_b, head_w, f));
}

__global__ __launch_bounds__(256) void node_kernel_fallback(
    const float* __restrict__ xf, const float* __restrict__ delta_acc,
    const float* __restrict__ head_b, float* __restrict__ out, int N)
{
    int n = blockIdx.x * 256 + threadIdx.x;
    if (n >= N) return;
    float delta = delta_acc[n] + head_b[0];
    float v = xf[4 * n] + delta;
    float sp = fmaxf(v, 0.0f) + log1pf(expf(-fabsf(v)));
    out[n] = sp;
    out[N + n] = delta;
}

// ---------------- host ----------------
static inline size_t align_up(size_t v, size_t a) { return (v + a - 1) & ~(a - 1); }

extern "C" void kernel_launch(void* const* d_in, const int* in_sizes, int n_in,
                              void* d_out, int out_size, void* d_ws, size_t ws_size,
                              hipStream_t stream) {
    const float4* x      = (const float4*)d_in[0];
    const float2* pos    = (const float2*)d_in[1];
    const float*  mlp_w  = (const float*)d_in[2];
    const float*  mlp_b  = (const float*)d_in[3];
    const float*  head_w = (const float*)d_in[4];
    const float*  head_b = (const float*)d_in[5];
    const int*    ei     = (const int*)d_in[6];

    int N = in_sizes[0] / 4;   // 100000
    int E = in_sizes[6] / 2;   // 3200000
    const int* srcs = ei;
    const int* dsts = ei + E;
    int B  = (N + BNODES - 1) / BNODES;   // 391
    int PB = (B + 1) >> 1;                // 196

    // zero-init region (one memset): g_ptr64 + ovf_cnt + bdone + delta1
    size_t off = 0;
    unsigned long long* g_ptr64 = (unsigned long long*)((char*)d_ws + off);
    off = align_up(off + (size_t)PB * 8, 64);
    int* ovf_cnt = (int*)((char*)d_ws + off);
    off = align_up(off + 64, 64);
    int* bdone = (int*)((char*)d_ws + off);
    off = align_up(off + (size_t)MAXB * 4, 256);
    float* delta1 = (float*)((char*)d_ws + off);
    off += (size_t)N * 4;
    size_t zero_bytes = off;
    off = align_up(off, 256);
    float4* xpos = (float4*)((char*)d_ws + off);
    off = align_up(off + (size_t)N * 32, 256);
    uint4* wbuf = (uint4*)((char*)d_ws + off);
    off = align_up(off + (size_t)4 * 64 * 16, 256);
    int2* ovf = (int2*)((char*)d_ws + off);
    off = align_up(off + (size_t)OVF_CAP * 8, 256);
    unsigned int* sorted = (unsigned int*)((char*)d_ws + off);
    size_t off_end = off + (size_t)B * CAP * 4;

    int ksh = 2;   // KPART = 4 (R22 experiment; was 3)
    bool fast = (off_end <= ws_size) && (B <= MAXB);

    if (fast) {
        hipMemsetAsync(d_ws, 0, zero_bytes, stream);
        int sgrid = (E + LSTAGE - 1) / LSTAGE;   // 250
        scatter_kernel<<<sgrid, BLK_SC, 0, stream>>>(
            srcs, dsts, E, B, N, x, pos, mlp_w,
            xpos, wbuf, g_ptr64, sorted, ovf, ovf_cnt);
        compute_kernel<<<B << ksh, BLK_C, 0, stream>>>(
            xpos, wbuf, mlp_w, mlp_b, head_w, head_b, sorted, g_ptr64,
            ovf, ovf_cnt, delta1, bdone, (float*)d_out, ksh, N);
    } else {
        float* delta = (float*)d_ws;
        hipMemsetAsync(delta, 0, (size_t)N * sizeof(float), stream);
        edge_kernel_fallback<<<(int)((E + 255) / 256), 256, 0, stream>>>(
            x, pos, mlp_w, mlp_b, head_w, srcs, dsts, delta, E);
        node_kernel_fallback<<<(N + 255) / 256, 256, 0, stream>>>(
            (const float*)x, delta, head_b, (float*)d_out, N);
    }
}

// Round 18
// 142.614 us; speedup vs baseline: 1.0121x; 1.0121x over previous
//
#include <hip/hip_runtime.h>
#include <hip/hip_bf16.h>

// N=100000, E=3200000, C=4, H=64. f32 inputs; edge_index int32;
// output concat(pm10_next[N], delta[N]) f32.
//
// R23 = FINAL: R18 champion verbatim (measured 141.8us / 142.3us; session
// start 187.6us -> -24%). ksh=3 (R22's KPART=4 regressed to 144.3).
//   memset(ctrs+delta1) -> scatter(sort+prep) -> compute(MFMA+fused
//   fence-free finalize via coherent atomics + bdone last-block).
// Ledger (what's refuted, with counters):
//  R22 KPART=4: compute flat 50.5us, total +2 (prologue not marginal cost)
//  R20 boundary removal: ~1us (boundary cost model refuted)
//  R19 chunk-major/etab: compute +11.6us > scatter -7us
//  R17 period-4 pipeline: compute 47.5->54 (VGPR+chain depth)
//  R16 cooperative fusion: phases 2.5x slower (spin-sync interference)
//  R14 6 blocks/CU: L2 thrash, +31MB traffic
//  R13 random global f32 atomics: ~31B HBM each (100MB WRITE)
//  R12/R15 scatter occupancy x2: neutral twice
//  R11 per-block __threadfence: L2 flush storm (WRITE 3->29MB)
// Shipped: counting sort + LDS accumulation, swapped-operand MFMA epilogue
// (2-shfl reduce), period-3 gather pipeline, drows LDS staging, one-pass
// scatter ranking, fence-free coherent-atomic fused finalize.

#define HID    64
#define EPSV   1e-8f
#define BNODES 256
#define CAP    10240        // mean 8192, sigma ~90 -> +22 sigma
#define MAXB   512
#define BLK_SC 512
#define RPT_SC 25           // edges held per scatter thread
#define LSTAGE (BLK_SC * RPT_SC)   // 12800 payloads staged in LDS
#define BLK_C  256
#define SLOTW  20           // dwords per staged edge slot (80B, 16B aligned)
#define OVF_CAP 65536

typedef _Float16 half8 __attribute__((ext_vector_type(8)));
typedef _Float16 half2_t __attribute__((ext_vector_type(2)));
typedef float f32x4 __attribute__((ext_vector_type(4)));

__device__ __forceinline__ unsigned int packh2(float a, float b) {
    union { half2_t h; unsigned int u; } v;
    v.h = half2_t{(_Float16)a, (_Float16)b};
    return v.u;
}

__device__ __forceinline__ void feat_from_rows(float4 xs, float4 ps4,
                                               float4 xd, float4 pd4,
                                               float* f) {
    float d0 = ps4.x - pd4.x;
    float d1 = ps4.y - pd4.y;
    float dist = sqrtf(fmaf(d0, d0, fmaf(d1, d1, EPSV)));
    float inv = 1.0f / dist;
    float wind = (xs.y * d0 + xs.z * d1) * inv;
    f[0] = xd.x; f[1] = xd.y; f[2] = xd.z; f[3] = xd.w;
    f[4] = xs.x; f[5] = xs.y; f[6] = xs.z; f[7] = xs.w;
    f[8] = wind; f[9] = dist;
}

__device__ __forceinline__ float mlp_scalar_g(const float* __restrict__ mlp_w,
                                              const float* __restrict__ mlp_b,
                                              const float* __restrict__ head_w,
                                              const float* f) {
    float sacc = 0.0f;
    for (int h = 0; h < HID; h++) {
        const float* wr = mlp_w + h * 10;
        float a = mlp_b[h];
        a = fmaf(wr[0], f[0], a); a = fmaf(wr[1], f[1], a);
        a = fmaf(wr[2], f[2], a); a = fmaf(wr[3], f[3], a);
        a = fmaf(wr[4], f[4], a); a = fmaf(wr[5], f[5], a);
        a = fmaf(wr[6], f[6], a); a = fmaf(wr[7], f[7], a);
        a = fmaf(wr[8], f[8], a); a = fmaf(wr[9], f[9], a);
        a = fmaxf(a, 0.0f);
        sacc = fmaf(head_w[h], a, sacc);
    }
    return sacc;
}

// ---------------- scatter (+prep fused): one-pass counting sort ----------------
__global__ __launch_bounds__(BLK_SC) void scatter_kernel(
    const int* __restrict__ srcs, const int* __restrict__ dsts,
    int E, int B, int N,
    const float4* __restrict__ x, const float2* __restrict__ pos,
    const float* __restrict__ mlp_w,
    float4* __restrict__ xpos, uint4* __restrict__ wbuf,
    unsigned long long* g_ptr64, unsigned int* __restrict__ sorted,
    int2* __restrict__ ovf, int* ovf_cnt)
{
    __shared__ int hist[MAXB];          // counts (atomic returns = rank)
    __shared__ int base[MAXB];          // global base per bucket (this block)
    __shared__ int pfx[MAXB];           // local exclusive prefix
    __shared__ int wsum[BLK_SC / 64];
    __shared__ unsigned int lpay[LSTAGE];   // payloads, local-sorted order
    __shared__ unsigned int ldst[LSTAGE];   // global dest indices

    int tid  = threadIdx.x;
    int lane = tid & 63;
    int wid  = tid >> 6;
    int lo = blockIdx.x * LSTAGE;

    int es[RPT_SC], ed[RPT_SC];
    bool ev[RPT_SC];
    #pragma unroll
    for (int r = 0; r < RPT_SC; r++) {
        int e = lo + r * BLK_SC + tid;
        bool okr = (e < E);
        ev[r] = okr;
        int ee = okr ? e : 0;
        es[r] = srcs[ee];
        ed[r] = dsts[ee];
    }

    for (int b2 = tid; b2 < MAXB; b2 += BLK_SC) hist[b2] = 0;

    // fused prep: pack x+pos into xpos rows (block-sliced)
    {
        int nper = (N + gridDim.x - 1) / gridDim.x;
        int n0 = blockIdx.x * nper;
        int n1 = min(n0 + nper, N);
        for (int n = n0 + tid; n < n1; n += BLK_SC) {
            float4 xr = x[n];
            float2 pr = pos[n];
            xpos[2 * n]     = xr;
            xpos[2 * n + 1] = make_float4(pr.x, pr.y, 0.0f, 0.0f);
        }
    }
    // fused prep: block 0 builds f16 weight fragments (A-operand layout)
    if (blockIdx.x == 0 && tid < 64) {
        int colw = tid & 15, quadw = tid >> 4;
        #pragma unroll
        for (int c = 0; c < 4; c++) {
            int h = c * 16 + colw;
            half8 wf = half8{0, 0, 0, 0, 0, 0, 0, 0};
            if (quadw == 0) {
                #pragma unroll
                for (int j = 0; j < 8; j++) wf[j] = (_Float16)mlp_w[h * 10 + j];
            } else if (quadw == 1) {
                wf[0] = (_Float16)mlp_w[h * 10 + 8];
                wf[1] = (_Float16)mlp_w[h * 10 + 9];
            }
            union { half8 h8; uint4 u4; } cv;
            cv.h8 = wf;
            wbuf[c * 64 + tid] = cv.u4;
        }
    }
    __syncthreads();

    // Phase 1: single atomic pass; atomic return IS the rank.
    // Reuse regs: es[r] <- payload, ed[r] <- (bucket<<14)|rank.
    #pragma unroll
    for (int r = 0; r < RPT_SC; r++) {
        if (ev[r]) {
            int b = ed[r] >> 8;
            int rk = atomicAdd(&hist[b], 1);
            es[r] = (es[r] << 8) | (ed[r] & 255);
            ed[r] = (b << 14) | rk;       // b<=511 (9b), rk<12800 (14b)
        }
    }
    __syncthreads();

    // Phase 2: global reservation (u64-paired) + local exclusive scan
    int PB = (B + 1) >> 1;
    for (int p = tid; p < PB; p += BLK_SC) {
        int b0 = 2 * p, b1 = 2 * p + 1;
        unsigned long long h0 = (unsigned int)hist[b0];
        unsigned long long h1 = (b1 < B) ? (unsigned int)hist[b1] : 0ull;
        unsigned long long comb = h0 | (h1 << 32);
        unsigned long long old = 0ull;
        if (comb) old = atomicAdd(&g_ptr64[p], comb);
        base[b0] = (int)(old & 0xffffffffull);
        if (b1 < B) base[b1] = (int)(old >> 32);
    }
    int v = hist[tid];          // MAXB == BLK_SC: one bucket per thread
    int xs_ = v;
    #pragma unroll
    for (int m = 1; m < 64; m <<= 1) {
        int y = __shfl_up(xs_, m, 64);
        if (lane >= m) xs_ += y;
    }
    if (lane == 63) wsum[wid] = xs_;
    __syncthreads();
    if (tid == 0) {
        int a = 0;
        #pragma unroll
        for (int j = 0; j < BLK_SC / 64; j++) { int t = wsum[j]; wsum[j] = a; a += t; }
    }
    __syncthreads();
    pfx[tid] = wsum[wid] + xs_ - v;
    __syncthreads();

    // Phase 3: stage payload + precomputed global destination
    #pragma unroll
    for (int r = 0; r < RPT_SC; r++) {
        if (ev[r]) {
            int b  = ed[r] >> 14;
            int rk = ed[r] & 0x3FFF;
            int p  = pfx[b] + rk;
            unsigned int pay = (unsigned int)es[r];
            lpay[p] = pay;
            int rel = base[b] + rk;
            if (rel < CAP) {
                ldst[p] = (unsigned int)b * CAP + (unsigned int)rel;
            } else {
                ldst[p] = 0xFFFFFFFFu;
                int o = atomicAdd(ovf_cnt, 1);
                if (o < OVF_CAP)
                    ovf[o] = make_int2((int)(pay >> 8), (b << 8) | (int)(pay & 255u));
            }
        }
    }
    __syncthreads();

    // Phase 4: dense block-linear copy-out (full lane util, coalesced dest)
    int cnt_blk = min(E - lo, LSTAGE);
    for (int t = tid; t < cnt_blk; t += BLK_SC) {
        unsigned int d = ldst[t];
        if (d != 0xFFFFFFFFu) sorted[d] = lpay[t];
    }
}

// ------- compute: MFMA MLP + bucket reduce + fence-free fused finalize -------
__global__ __launch_bounds__(BLK_C, 4) void compute_kernel(
    const float4* __restrict__ xpos,
    const uint4* __restrict__ wbuf,
    const float* __restrict__ mlp_w, const float* __restrict__ mlp_b,
    const float* __restrict__ head_w, const float* __restrict__ head_b,
    const unsigned int* __restrict__ sorted,
    const unsigned long long* __restrict__ g_ptr64,
    const int2* __restrict__ ovf, const int* __restrict__ ovf_cnt,
    float* __restrict__ delta1, int* __restrict__ bdone,
    float* __restrict__ out, int ksh, int N)
{
    // Per-wave B staging: 64 slots x 20 dwords. Dwords 0-4: f16x2 feats
    // k0..k9; 5-15: zeros (k10..k31).
    __shared__ __align__(16) unsigned int stage[4 * 64 * SLOTW];   // 20 KB
    __shared__ __align__(16) float4 drows[2 * BNODES];             // 8 KB dst rows
    __shared__ float acc[BNODES];
    __shared__ int lastflag;
    int tid  = threadIdx.x;
    int wave = tid >> 6;
    int lane = tid & 63;
    int col  = lane & 15;
    int quad = lane >> 4;
    int wbase = wave * 64 * SLOTW;

    int b    = blockIdx.x >> ksh;
    int part = blockIdx.x & ((1 << ksh) - 1);
    int nbase = b << 8;

    acc[tid] = 0.0f;

    // stage this bucket's 256 dst rows (clamped for the tail bucket)
    {
        int lim = 2 * N - 1;
        drows[tid]       = xpos[min(2 * nbase + tid, lim)];
        drows[tid + 256] = xpos[min(2 * nbase + tid + 256, lim)];
    }

    {   // zero the static-zero region of this lane's slot (once)
        unsigned int* slotp = &stage[wbase + lane * SLOTW];
        slotp[5] = 0u;
        *(uint2*)(slotp + 6) = make_uint2(0u, 0u);
        *(uint4*)(slotp + 8) = make_uint4(0u, 0u, 0u, 0u);
        *(uint4*)(slotp + 12) = make_uint4(0u, 0u, 0u, 0u);
    }

    // A-operand weight fragments: 4 vector loads from precomputed buffer
    half8 wfr[4];
    f32x4 bias4[4], hw4[4];
    #pragma unroll
    for (int c = 0; c < 4; c++) {
        union { uint4 u4; half8 h8; } cv;
        cv.u4 = wbuf[c * 64 + lane];
        wfr[c] = cv.h8;
        bias4[c] = *(const f32x4*)&mlp_b[c * 16 + quad * 4];
        hw4[c]   = *(const f32x4*)&head_w[c * 16 + quad * 4];
    }
    __syncthreads();

    unsigned long long gp = g_ptr64[b >> 1];
    int cnt = (b & 1) ? (int)(gp >> 32) : (int)(gp & 0xffffffffull);
    cnt = min(cnt, CAP);
    int e0 = (cnt * part) >> ksh;
    int e1 = (cnt * (part + 1)) >> ksh;
    const unsigned int* sp = sorted + (size_t)b * CAP;

    if (e0 < e1) {
        // Period-3 software pipeline (R10-proven; R17's period-4 regressed):
        //   step k: consume (p_k, x_k); gather x_{k+1} from p_{k+1};
        //           prefetch p_{k+2}.
        unsigned int p0, p1, p2;
        float4 xA, pA, xB, pB, xC, pC;
        {
            int i = e0 + tid;
            p0 = sp[(i < e1) ? i : e0];
            int i1 = i + BLK_C;
            p1 = sp[(i1 < e1) ? i1 : e0];
            int s0 = (int)(p0 >> 8);
            xA = xpos[2 * s0];
            pA = xpos[2 * s0 + 1];
        }

        auto body = [&](int i0, unsigned int pc, unsigned int pn,
                        unsigned int& pn2, float4 xc, float4 psc,
                        float4& xn, float4& psn) {
            bool cok = (i0 + tid) < e1;
            int dl = (int)(pc & 255u);
            // prefetch payload 2 ahead + gathers for next iter (independent)
            int i2 = i0 + 2 * BLK_C + tid;
            pn2 = sp[(i2 < e1) ? i2 : e0];
            int sn = (int)(pn >> 8);
            xn  = xpos[2 * sn];
            psn = xpos[2 * sn + 1];
            // current features: dst side from LDS
            float4 xd  = drows[2 * dl];
            float4 pd4 = drows[2 * dl + 1];
            float f[10];
            feat_from_rows(xc, psc, xd, pd4, f);
            unsigned int* slotp = &stage[wbase + lane * SLOTW];
            *(uint4*)slotp = make_uint4(packh2(f[0], f[1]), packh2(f[2], f[3]),
                                        packh2(f[4], f[5]), packh2(f[6], f[7]));
            slotp[4] = packh2(f[8], f[9]);

            float mysum = 0.0f;
            #pragma unroll
            for (int eg = 0; eg < 4; eg++) {
                const half8 fb = *(const half8*)&stage[wbase + (eg * 16 + col) * SLOTW + quad * 4];
                float sacc = 0.0f;
                #pragma unroll
                for (int c = 0; c < 4; c++) {
                    f32x4 d = __builtin_amdgcn_mfma_f32_16x16x32_f16(wfr[c], fb, bias4[c], 0, 0, 0);
                    sacc = fmaf(hw4[c][0], fmaxf(d[0], 0.f), sacc);
                    sacc = fmaf(hw4[c][1], fmaxf(d[1], 0.f), sacc);
                    sacc = fmaf(hw4[c][2], fmaxf(d[2], 0.f), sacc);
                    sacc = fmaf(hw4[c][3], fmaxf(d[3], 0.f), sacc);
                }
                sacc += __shfl_xor(sacc, 16, 64);
                sacc += __shfl_xor(sacc, 32, 64);
                if (quad == eg) mysum = sacc;
            }
            if (cok) atomicAdd(&acc[dl], mysum);   // ds_add_f32
        };

        int i0 = e0;
        for (;;) {
            body(i0, p0, p1, p2, xA, pA, xB, pB);   // consume p0/xA
            i0 += BLK_C; if (i0 >= e1) break;
            body(i0, p1, p2, p0, xB, pB, xC, pC);   // consume p1/xB
            i0 += BLK_C; if (i0 >= e1) break;
            body(i0, p2, p0, p1, xC, pC, xA, pA);   // consume p2/xC
            i0 += BLK_C; if (i0 >= e1) break;
        }
    }
    __syncthreads();

    // accumulate this part's bucket sums into the single coherent plane.
    // Atomics execute at the memory-side coherent point -> visible to all
    // XCDs once complete; NO threadfence (= no L2 flush) needed.
    {
        int n = nbase + tid;
        if (n < N && acc[tid] != 0.0f)
            unsafeAtomicAdd(&delta1[n], acc[tid]);
    }

    // fused overflow path (normally *ovf_cnt == 0); atomic adds, same plane
    if (part == 0) {
        int oc = min(*ovf_cnt, OVF_CAP);
        for (int idx = tid; idx < oc; idx += BLK_C) {
            int2 sd = ovf[idx];
            if ((sd.y >> 8) == b && sd.y < N) {
                float f[10];
                feat_from_rows(xpos[2 * sd.x], xpos[2 * sd.x + 1],
                               xpos[2 * sd.y], xpos[2 * sd.y + 1], f);
                unsafeAtomicAdd(&delta1[sd.y], mlp_scalar_g(mlp_w, mlp_b, head_w, f));
            }
        }
    }

    // wait for OWN atomics only (cheap; they are globally visible once
    // vmcnt retires them), then signal; last arriving part finalizes.
    asm volatile("s_waitcnt vmcnt(0)" ::: "memory");
    __syncthreads();
    if (tid == 0) {
        int prev = atomicAdd(&bdone[b], 1);
        lastflag = (prev == (1 << ksh) - 1) ? 1 : 0;
    }
    __syncthreads();
    if (lastflag) {
        int n = nbase + tid;
        if (n < N) {
            // coherent read of the fully-accumulated value
            float delta = atomicAdd(&delta1[n], 0.0f) + head_b[0];
            float v = drows[2 * tid].x + delta;   // x[n].x still in LDS
            float sp = fmaxf(v, 0.0f) + log1pf(expf(-fabsf(v)));
            out[n] = sp;
            out[N + n] = delta;
        }
    }
}

// ---------------- fallback path (ws too small) ----------------
__global__ __launch_bounds__(256) void edge_kernel_fallback(
    const float4* __restrict__ x, const float2* __restrict__ pos,
    const float* __restrict__ mlp_w, const float* __restrict__ mlp_b,
    const float* __restrict__ head_w,
    const int* __restrict__ srcs, const int* __restrict__ dsts,
    float* __restrict__ delta_acc, int E)
{
    long e = (long)blockIdx.x * 256 + threadIdx.x;
    if (e >= E) return;
    int s = srcs[e], d = dsts[e];
    float4 xs = x[s], xd = x[d];
    float2 ps = pos[s], pd = pos[d];
    float f[10];
    feat_from_rows(xs, make_float4(ps.x, ps.y, 0, 0),
                   xd, make_float4(pd.x, pd.y, 0, 0), f);
    unsafeAtomicAdd(&delta_acc[d], mlp_scalar_g(mlp_w, mlp_b, head_w, f));
}

__global__ __launch_bounds__(256) void node_kernel_fallback(
    const float* __restrict__ xf, const float* __restrict__ delta_acc,
    const float* __restrict__ head_b, float* __restrict__ out, int N)
{
    int n = blockIdx.x * 256 + threadIdx.x;
    if (n >= N) return;
    float delta = delta_acc[n] + head_b[0];
    float v = xf[4 * n] + delta;
    float sp = fmaxf(v, 0.0f) + log1pf(expf(-fabsf(v)));
    out[n] = sp;
    out[N + n] = delta;
}

// ---------------- host ----------------
static inline size_t align_up(size_t v, size_t a) { return (v + a - 1) & ~(a - 1); }

extern "C" void kernel_launch(void* const* d_in, const int* in_sizes, int n_in,
                              void* d_out, int out_size, void* d_ws, size_t ws_size,
                              hipStream_t stream) {
    const float4* x      = (const float4*)d_in[0];
    const float2* pos    = (const float2*)d_in[1];
    const float*  mlp_w  = (const float*)d_in[2];
    const float*  mlp_b  = (const float*)d_in[3];
    const float*  head_w = (const float*)d_in[4];
    const float*  head_b = (const float*)d_in[5];
    const int*    ei     = (const int*)d_in[6];

    int N = in_sizes[0] / 4;   // 100000
    int E = in_sizes[6] / 2;   // 3200000
    const int* srcs = ei;
    const int* dsts = ei + E;
    int B  = (N + BNODES - 1) / BNODES;   // 391
    int PB = (B + 1) >> 1;                // 196

    // zero-init region (one memset): g_ptr64 + ovf_cnt + bdone + delta1
    size_t off = 0;
    unsigned long long* g_ptr64 = (unsigned long long*)((char*)d_ws + off);
    off = align_up(off + (size_t)PB * 8, 64);
    int* ovf_cnt = (int*)((char*)d_ws + off);
    off = align_up(off + 64, 64);
    int* bdone = (int*)((char*)d_ws + off);
    off = align_up(off + (size_t)MAXB * 4, 256);
    float* delta1 = (float*)((char*)d_ws + off);
    off += (size_t)N * 4;
    size_t zero_bytes = off;
    off = align_up(off, 256);
    float4* xpos = (float4*)((char*)d_ws + off);
    off = align_up(off + (size_t)N * 32, 256);
    uint4* wbuf = (uint4*)((char*)d_ws + off);
    off = align_up(off + (size_t)4 * 64 * 16, 256);
    int2* ovf = (int2*)((char*)d_ws + off);
    off = align_up(off + (size_t)OVF_CAP * 8, 256);
    unsigned int* sorted = (unsigned int*)((char*)d_ws + off);
    size_t off_end = off + (size_t)B * CAP * 4;

    int ksh = 3;   // KPART = 8 (champion; KPART=4 measured worse)
    bool fast = (off_end <= ws_size) && (B <= MAXB);

    if (fast) {
        hipMemsetAsync(d_ws, 0, zero_bytes, stream);
        int sgrid = (E + LSTAGE - 1) / LSTAGE;   // 250
        scatter_kernel<<<sgrid, BLK_SC, 0, stream>>>(
            srcs, dsts, E, B, N, x, pos, mlp_w,
            xpos, wbuf, g_ptr64, sorted, ovf, ovf_cnt);
        compute_kernel<<<B << ksh, BLK_C, 0, stream>>>(
            xpos, wbuf, mlp_w, mlp_b, head_w, head_b, sorted, g_ptr64,
            ovf, ovf_cnt, delta1, bdone, (float*)d_out, ksh, N);
    } else {
        float* delta = (float*)d_ws;
        hipMemsetAsync(delta, 0, (size_t)N * sizeof(float), stream);
        edge_kernel_fallback<<<(int)((E + 255) / 256), 256, 0, stream>>>(
            x, pos, mlp_w, mlp_b, head_w, srcs, dsts, delta, E);
        node_kernel_fallback<<<(N + 255) / 256, 256, 0, stream>>>(
            (const float*)x, delta, head_b, (float*)d_out, N);
    }
}

// Round 19
// 139.669 us; speedup vs baseline: 1.0334x; 1.0211x over previous
//
#include <hip/hip_runtime.h>
#include <hip/hip_bf16.h>

// N=100000, E=3200000, C=4, H=64. f32 inputs; edge_index int32;
// output concat(pm10_next[N], delta[N]) f32.
//
// R24 = R18 champion (141.8/142.3/142.6us) + ONE change: xpos packed
// array DELETED. Compute gathers x[s] (16B) + pos[s] (8B) directly:
// 24B/edge src-side instead of 32B, working set 3.2->2.4MB (L2-friendlier
// per R14), pos pipeline regs float4->float2, scatter loses its packing
// pass (5.6MB traffic removed). drows -> dx[256](4KB)+dp[256](2KB).
// Ledger: R22 KPART=4 flat; R20 boundary ~1us; R19 etab +11.6us;
// R17 period-4 regressed; R16 coop 2.5x slower; R14 6 blk/CU L2 thrash;
// R13 random atomics ~31B HBM; R12/R15 scatter occupancy neutral;
// R11 per-block fence storm.

#define HID    64
#define EPSV   1e-8f
#define BNODES 256
#define CAP    10240        // mean 8192, sigma ~90 -> +22 sigma
#define MAXB   512
#define BLK_SC 512
#define RPT_SC 25           // edges held per scatter thread
#define LSTAGE (BLK_SC * RPT_SC)   // 12800 payloads staged in LDS
#define BLK_C  256
#define SLOTW  20           // dwords per staged edge slot (80B, 16B aligned)
#define OVF_CAP 65536

typedef _Float16 half8 __attribute__((ext_vector_type(8)));
typedef _Float16 half2_t __attribute__((ext_vector_type(2)));
typedef float f32x4 __attribute__((ext_vector_type(4)));

__device__ __forceinline__ unsigned int packh2(float a, float b) {
    union { half2_t h; unsigned int u; } v;
    v.h = half2_t{(_Float16)a, (_Float16)b};
    return v.u;
}

__device__ __forceinline__ void feat_make(float4 xs, float2 ps,
                                          float4 xd, float2 pd,
                                          float* f) {
    float d0 = ps.x - pd.x;
    float d1 = ps.y - pd.y;
    float dist = sqrtf(fmaf(d0, d0, fmaf(d1, d1, EPSV)));
    float inv = 1.0f / dist;
    float wind = (xs.y * d0 + xs.z * d1) * inv;
    f[0] = xd.x; f[1] = xd.y; f[2] = xd.z; f[3] = xd.w;
    f[4] = xs.x; f[5] = xs.y; f[6] = xs.z; f[7] = xs.w;
    f[8] = wind; f[9] = dist;
}

__device__ __forceinline__ float mlp_scalar_g(const float* __restrict__ mlp_w,
                                              const float* __restrict__ mlp_b,
                                              const float* __restrict__ head_w,
                                              const float* f) {
    float sacc = 0.0f;
    for (int h = 0; h < HID; h++) {
        const float* wr = mlp_w + h * 10;
        float a = mlp_b[h];
        a = fmaf(wr[0], f[0], a); a = fmaf(wr[1], f[1], a);
        a = fmaf(wr[2], f[2], a); a = fmaf(wr[3], f[3], a);
        a = fmaf(wr[4], f[4], a); a = fmaf(wr[5], f[5], a);
        a = fmaf(wr[6], f[6], a); a = fmaf(wr[7], f[7], a);
        a = fmaf(wr[8], f[8], a); a = fmaf(wr[9], f[9], a);
        a = fmaxf(a, 0.0f);
        sacc = fmaf(head_w[h], a, sacc);
    }
    return sacc;
}

// ---------------- scatter (+wbuf prep): one-pass counting sort ----------------
__global__ __launch_bounds__(BLK_SC) void scatter_kernel(
    const int* __restrict__ srcs, const int* __restrict__ dsts,
    int E, int B,
    const float* __restrict__ mlp_w,
    uint4* __restrict__ wbuf,
    unsigned long long* g_ptr64, unsigned int* __restrict__ sorted,
    int2* __restrict__ ovf, int* ovf_cnt)
{
    __shared__ int hist[MAXB];          // counts (atomic returns = rank)
    __shared__ int base[MAXB];          // global base per bucket (this block)
    __shared__ int pfx[MAXB];           // local exclusive prefix
    __shared__ int wsum[BLK_SC / 64];
    __shared__ unsigned int lpay[LSTAGE];   // payloads, local-sorted order
    __shared__ unsigned int ldst[LSTAGE];   // global dest indices

    int tid  = threadIdx.x;
    int lane = tid & 63;
    int wid  = tid >> 6;
    int lo = blockIdx.x * LSTAGE;

    int es[RPT_SC], ed[RPT_SC];
    bool ev[RPT_SC];
    #pragma unroll
    for (int r = 0; r < RPT_SC; r++) {
        int e = lo + r * BLK_SC + tid;
        bool okr = (e < E);
        ev[r] = okr;
        int ee = okr ? e : 0;
        es[r] = srcs[ee];
        ed[r] = dsts[ee];
    }

    for (int b2 = tid; b2 < MAXB; b2 += BLK_SC) hist[b2] = 0;

    // fused prep: block 0 builds f16 weight fragments (A-operand layout)
    if (blockIdx.x == 0 && tid < 64) {
        int colw = tid & 15, quadw = tid >> 4;
        #pragma unroll
        for (int c = 0; c < 4; c++) {
            int h = c * 16 + colw;
            half8 wf = half8{0, 0, 0, 0, 0, 0, 0, 0};
            if (quadw == 0) {
                #pragma unroll
                for (int j = 0; j < 8; j++) wf[j] = (_Float16)mlp_w[h * 10 + j];
            } else if (quadw == 1) {
                wf[0] = (_Float16)mlp_w[h * 10 + 8];
                wf[1] = (_Float16)mlp_w[h * 10 + 9];
            }
            union { half8 h8; uint4 u4; } cv;
            cv.h8 = wf;
            wbuf[c * 64 + tid] = cv.u4;
        }
    }
    __syncthreads();

    // Phase 1: single atomic pass; atomic return IS the rank.
    // Reuse regs: es[r] <- payload, ed[r] <- (bucket<<14)|rank.
    #pragma unroll
    for (int r = 0; r < RPT_SC; r++) {
        if (ev[r]) {
            int b = ed[r] >> 8;
            int rk = atomicAdd(&hist[b], 1);
            es[r] = (es[r] << 8) | (ed[r] & 255);
            ed[r] = (b << 14) | rk;       // b<=511 (9b), rk<12800 (14b)
        }
    }
    __syncthreads();

    // Phase 2: global reservation (u64-paired) + local exclusive scan
    int PB = (B + 1) >> 1;
    for (int p = tid; p < PB; p += BLK_SC) {
        int b0 = 2 * p, b1 = 2 * p + 1;
        unsigned long long h0 = (unsigned int)hist[b0];
        unsigned long long h1 = (b1 < B) ? (unsigned int)hist[b1] : 0ull;
        unsigned long long comb = h0 | (h1 << 32);
        unsigned long long old = 0ull;
        if (comb) old = atomicAdd(&g_ptr64[p], comb);
        base[b0] = (int)(old & 0xffffffffull);
        if (b1 < B) base[b1] = (int)(old >> 32);
    }
    int v = hist[tid];          // MAXB == BLK_SC: one bucket per thread
    int xs_ = v;
    #pragma unroll
    for (int m = 1; m < 64; m <<= 1) {
        int y = __shfl_up(xs_, m, 64);
        if (lane >= m) xs_ += y;
    }
    if (lane == 63) wsum[wid] = xs_;
    __syncthreads();
    if (tid == 0) {
        int a = 0;
        #pragma unroll
        for (int j = 0; j < BLK_SC / 64; j++) { int t = wsum[j]; wsum[j] = a; a += t; }
    }
    __syncthreads();
    pfx[tid] = wsum[wid] + xs_ - v;
    __syncthreads();

    // Phase 3: stage payload + precomputed global destination
    #pragma unroll
    for (int r = 0; r < RPT_SC; r++) {
        if (ev[r]) {
            int b  = ed[r] >> 14;
            int rk = ed[r] & 0x3FFF;
            int p  = pfx[b] + rk;
            unsigned int pay = (unsigned int)es[r];
            lpay[p] = pay;
            int rel = base[b] + rk;
            if (rel < CAP) {
                ldst[p] = (unsigned int)b * CAP + (unsigned int)rel;
            } else {
                ldst[p] = 0xFFFFFFFFu;
                int o = atomicAdd(ovf_cnt, 1);
                if (o < OVF_CAP)
                    ovf[o] = make_int2((int)(pay >> 8), (b << 8) | (int)(pay & 255u));
            }
        }
    }
    __syncthreads();

    // Phase 4: dense block-linear copy-out (full lane util, coalesced dest)
    int cnt_blk = min(E - lo, LSTAGE);
    for (int t = tid; t < cnt_blk; t += BLK_SC) {
        unsigned int d = ldst[t];
        if (d != 0xFFFFFFFFu) sorted[d] = lpay[t];
    }
}

// ------- compute: MFMA MLP + bucket reduce + fence-free fused finalize -------
__global__ __launch_bounds__(BLK_C, 4) void compute_kernel(
    const float4* __restrict__ x, const float2* __restrict__ pos,
    const uint4* __restrict__ wbuf,
    const float* __restrict__ mlp_w, const float* __restrict__ mlp_b,
    const float* __restrict__ head_w, const float* __restrict__ head_b,
    const unsigned int* __restrict__ sorted,
    const unsigned long long* __restrict__ g_ptr64,
    const int2* __restrict__ ovf, const int* __restrict__ ovf_cnt,
    float* __restrict__ delta1, int* __restrict__ bdone,
    float* __restrict__ out, int ksh, int N)
{
    // Per-wave B staging: 64 slots x 20 dwords. Dwords 0-4: f16x2 feats
    // k0..k9; 5-15: zeros (k10..k31).
    __shared__ __align__(16) unsigned int stage[4 * 64 * SLOTW];   // 20 KB
    __shared__ __align__(16) float4 dx[BNODES];                    // 4 KB dst x
    __shared__ __align__(8)  float2 dp[BNODES];                    // 2 KB dst pos
    __shared__ float acc[BNODES];
    __shared__ int lastflag;
    int tid  = threadIdx.x;
    int wave = tid >> 6;
    int lane = tid & 63;
    int col  = lane & 15;
    int quad = lane >> 4;
    int wbase = wave * 64 * SLOTW;

    int b    = blockIdx.x >> ksh;
    int part = blockIdx.x & ((1 << ksh) - 1);
    int nbase = b << 8;

    acc[tid] = 0.0f;

    // stage this bucket's 256 dst rows directly from x/pos (clamped tail)
    {
        int nn = min(nbase + tid, N - 1);
        dx[tid] = x[nn];
        dp[tid] = pos[nn];
    }

    {   // zero the static-zero region of this lane's slot (once)
        unsigned int* slotp = &stage[wbase + lane * SLOTW];
        slotp[5] = 0u;
        *(uint2*)(slotp + 6) = make_uint2(0u, 0u);
        *(uint4*)(slotp + 8) = make_uint4(0u, 0u, 0u, 0u);
        *(uint4*)(slotp + 12) = make_uint4(0u, 0u, 0u, 0u);
    }

    // A-operand weight fragments: 4 vector loads from precomputed buffer
    half8 wfr[4];
    f32x4 bias4[4], hw4[4];
    #pragma unroll
    for (int c = 0; c < 4; c++) {
        union { uint4 u4; half8 h8; } cv;
        cv.u4 = wbuf[c * 64 + lane];
        wfr[c] = cv.h8;
        bias4[c] = *(const f32x4*)&mlp_b[c * 16 + quad * 4];
        hw4[c]   = *(const f32x4*)&head_w[c * 16 + quad * 4];
    }
    __syncthreads();

    unsigned long long gp = g_ptr64[b >> 1];
    int cnt = (b & 1) ? (int)(gp >> 32) : (int)(gp & 0xffffffffull);
    cnt = min(cnt, CAP);
    int e0 = (cnt * part) >> ksh;
    int e1 = (cnt * (part + 1)) >> ksh;
    const unsigned int* sp = sorted + (size_t)b * CAP;

    if (e0 < e1) {
        // Period-3 software pipeline (proven):
        //   step k: consume (p_k, x_k); gather x_{k+1} from p_{k+1};
        //           prefetch p_{k+2}. Gathers now direct x[s]/pos[s].
        unsigned int p0, p1, p2;
        float4 xA, xB, xC;
        float2 pA, pB, pC;
        {
            int i = e0 + tid;
            p0 = sp[(i < e1) ? i : e0];
            int i1 = i + BLK_C;
            p1 = sp[(i1 < e1) ? i1 : e0];
            int s0 = (int)(p0 >> 8);
            xA = x[s0];
            pA = pos[s0];
        }

        auto body = [&](int i0, unsigned int pc, unsigned int pn,
                        unsigned int& pn2, float4 xc, float2 psc,
                        float4& xn, float2& psn) {
            bool cok = (i0 + tid) < e1;
            int dl = (int)(pc & 255u);
            // prefetch payload 2 ahead + gathers for next iter (independent)
            int i2 = i0 + 2 * BLK_C + tid;
            pn2 = sp[(i2 < e1) ? i2 : e0];
            int sn = (int)(pn >> 8);
            xn  = x[sn];
            psn = pos[sn];
            // current features: dst side from LDS
            float4 xd  = dx[dl];
            float2 pd2 = dp[dl];
            float f[10];
            feat_make(xc, psc, xd, pd2, f);
            unsigned int* slotp = &stage[wbase + lane * SLOTW];
            *(uint4*)slotp = make_uint4(packh2(f[0], f[1]), packh2(f[2], f[3]),
                                        packh2(f[4], f[5]), packh2(f[6], f[7]));
            slotp[4] = packh2(f[8], f[9]);

            float mysum = 0.0f;
            #pragma unroll
            for (int eg = 0; eg < 4; eg++) {
                const half8 fb = *(const half8*)&stage[wbase + (eg * 16 + col) * SLOTW + quad * 4];
                float sacc = 0.0f;
                #pragma unroll
                for (int c = 0; c < 4; c++) {
                    f32x4 d = __builtin_amdgcn_mfma_f32_16x16x32_f16(wfr[c], fb, bias4[c], 0, 0, 0);
                    sacc = fmaf(hw4[c][0], fmaxf(d[0], 0.f), sacc);
                    sacc = fmaf(hw4[c][1], fmaxf(d[1], 0.f), sacc);
                    sacc = fmaf(hw4[c][2], fmaxf(d[2], 0.f), sacc);
                    sacc = fmaf(hw4[c][3], fmaxf(d[3], 0.f), sacc);
                }
                sacc += __shfl_xor(sacc, 16, 64);
                sacc += __shfl_xor(sacc, 32, 64);
                if (quad == eg) mysum = sacc;
            }
            if (cok) atomicAdd(&acc[dl], mysum);   // ds_add_f32
        };

        int i0 = e0;
        for (;;) {
            body(i0, p0, p1, p2, xA, pA, xB, pB);   // consume p0/xA
            i0 += BLK_C; if (i0 >= e1) break;
            body(i0, p1, p2, p0, xB, pB, xC, pC);   // consume p1/xB
            i0 += BLK_C; if (i0 >= e1) break;
            body(i0, p2, p0, p1, xC, pC, xA, pA);   // consume p2/xC
            i0 += BLK_C; if (i0 >= e1) break;
        }
    }
    __syncthreads();

    // accumulate this part's bucket sums into the single coherent plane.
    // Atomics execute at the memory-side coherent point -> visible to all
    // XCDs once complete; NO threadfence (= no L2 flush) needed.
    {
        int n = nbase + tid;
        if (n < N && acc[tid] != 0.0f)
            unsafeAtomicAdd(&delta1[n], acc[tid]);
    }

    // fused overflow path (normally *ovf_cnt == 0); atomic adds, same plane
    if (part == 0) {
        int oc = min(*ovf_cnt, OVF_CAP);
        for (int idx = tid; idx < oc; idx += BLK_C) {
            int2 sd = ovf[idx];
            if ((sd.y >> 8) == b && sd.y < N) {
                float f[10];
                feat_make(x[sd.x], pos[sd.x], x[sd.y], pos[sd.y], f);
                unsafeAtomicAdd(&delta1[sd.y], mlp_scalar_g(mlp_w, mlp_b, head_w, f));
            }
        }
    }

    // wait for OWN atomics only (cheap; they are globally visible once
    // vmcnt retires them), then signal; last arriving part finalizes.
    asm volatile("s_waitcnt vmcnt(0)" ::: "memory");
    __syncthreads();
    if (tid == 0) {
        int prev = atomicAdd(&bdone[b], 1);
        lastflag = (prev == (1 << ksh) - 1) ? 1 : 0;
    }
    __syncthreads();
    if (lastflag) {
        int n = nbase + tid;
        if (n < N) {
            // coherent read of the fully-accumulated value
            float delta = atomicAdd(&delta1[n], 0.0f) + head_b[0];
            float v = dx[tid].x + delta;   // x[n].x still in LDS
            float sp = fmaxf(v, 0.0f) + log1pf(expf(-fabsf(v)));
            out[n] = sp;
            out[N + n] = delta;
        }
    }
}

// ---------------- fallback path (ws too small) ----------------
__global__ __launch_bounds__(256) void edge_kernel_fallback(
    const float4* __restrict__ x, const float2* __restrict__ pos,
    const float* __restrict__ mlp_w, const float* __restrict__ mlp_b,
    const float* __restrict__ head_w,
    const int* __restrict__ srcs, const int* __restrict__ dsts,
    float* __restrict__ delta_acc, int E)
{
    long e = (long)blockIdx.x * 256 + threadIdx.x;
    if (e >= E) return;
    int s = srcs[e], d = dsts[e];
    float f[10];
    feat_make(x[s], pos[s], x[d], pos[d], f);
    unsafeAtomicAdd(&delta_acc[d], mlp_scalar_g(mlp_w, mlp_b, head_w, f));
}

__global__ __launch_bounds__(256) void node_kernel_fallback(
    const float* __restrict__ xf, const float* __restrict__ delta_acc,
    const float* __restrict__ head_b, float* __restrict__ out, int N)
{
    int n = blockIdx.x * 256 + threadIdx.x;
    if (n >= N) return;
    float delta = delta_acc[n] + head_b[0];
    float v = xf[4 * n] + delta;
    float sp = fmaxf(v, 0.0f) + log1pf(expf(-fabsf(v)));
    out[n] = sp;
    out[N + n] = delta;
}

// ---------------- host ----------------
static inline size_t align_up(size_t v, size_t a) { return (v + a - 1) & ~(a - 1); }

extern "C" void kernel_launch(void* const* d_in, const int* in_sizes, int n_in,
                              void* d_out, int out_size, void* d_ws, size_t ws_size,
                              hipStream_t stream) {
    const float4* x      = (const float4*)d_in[0];
    const float2* pos    = (const float2*)d_in[1];
    const float*  mlp_w  = (const float*)d_in[2];
    const float*  mlp_b  = (const float*)d_in[3];
    const float*  head_w = (const float*)d_in[4];
    const float*  head_b = (const float*)d_in[5];
    const int*    ei     = (const int*)d_in[6];

    int N = in_sizes[0] / 4;   // 100000
    int E = in_sizes[6] / 2;   // 3200000
    const int* srcs = ei;
    const int* dsts = ei + E;
    int B  = (N + BNODES - 1) / BNODES;   // 391
    int PB = (B + 1) >> 1;                // 196

    // zero-init region (one memset): g_ptr64 + ovf_cnt + bdone + delta1
    size_t off = 0;
    unsigned long long* g_ptr64 = (unsigned long long*)((char*)d_ws + off);
    off = align_up(off + (size_t)PB * 8, 64);
    int* ovf_cnt = (int*)((char*)d_ws + off);
    off = align_up(off + 64, 64);
    int* bdone = (int*)((char*)d_ws + off);
    off = align_up(off + (size_t)MAXB * 4, 256);
    float* delta1 = (float*)((char*)d_ws + off);
    off += (size_t)N * 4;
    size_t zero_bytes = off;
    off = align_up(off, 256);
    uint4* wbuf = (uint4*)((char*)d_ws + off);
    off = align_up(off + (size_t)4 * 64 * 16, 256);
    int2* ovf = (int2*)((char*)d_ws + off);
    off = align_up(off + (size_t)OVF_CAP * 8, 256);
    unsigned int* sorted = (unsigned int*)((char*)d_ws + off);
    size_t off_end = off + (size_t)B * CAP * 4;

    int ksh = 3;   // KPART = 8 (champion; KPART=4 measured worse)
    bool fast = (off_end <= ws_size) && (B <= MAXB);

    if (fast) {
        hipMemsetAsync(d_ws, 0, zero_bytes, stream);
        int sgrid = (E + LSTAGE - 1) / LSTAGE;   // 250
        scatter_kernel<<<sgrid, BLK_SC, 0, stream>>>(
            srcs, dsts, E, B, mlp_w, wbuf, g_ptr64, sorted, ovf, ovf_cnt);
        compute_kernel<<<B << ksh, BLK_C, 0, stream>>>(
            x, pos, wbuf, mlp_w, mlp_b, head_w, head_b, sorted, g_ptr64,
            ovf, ovf_cnt, delta1, bdone, (float*)d_out, ksh, N);
    } else {
        float* delta = (float*)d_ws;
        hipMemsetAsync(delta, 0, (size_t)N * sizeof(float), stream);
        edge_kernel_fallback<<<(int)((E + 255) / 256), 256, 0, stream>>>(
            x, pos, mlp_w, mlp_b, head_w, srcs, dsts, delta, E);
        node_kernel_fallback<<<(N + 255) / 256, 256, 0, stream>>>(
            (const float*)x, delta, head_b, (float*)d_out, N);
    }
}